// Round 1
// baseline (677.820 us; speedup 1.0000x reference)
//
#include <hip/hip_runtime.h>
#include <hip/hip_bf16.h>
#include <stdint.h>
#include <stddef.h>

// Problem constants
#define BB 4
#define LL 2048
#define KNB 30
#define IND 128
#define OUTD 400
#define NGEMM 800           // 2*OUTD: [T | U] combined GEMM width
#define NQ (BB*LL)          // 8192 queries / rows
#define OUT_EIDX_OFF 98304000  // 4*2048*30*400

typedef short short8 __attribute__((ext_vector_type(8)));
typedef float f32x4 __attribute__((ext_vector_type(4)));

__device__ __forceinline__ unsigned short f2b(float f) {
    unsigned int u = __float_as_uint(f);
    unsigned int r = (u + 0x7FFFu + ((u >> 16) & 1u)) >> 16;  // RNE
    return (unsigned short)r;
}
__device__ __forceinline__ float b2f(unsigned short u) {
    return __uint_as_float(((unsigned int)u) << 16);
}

// ---------------------------------------------------------------------------
// K1: convert V -> bf16 (Vb), build transposed+concatenated W -> bf16 (Wt),
//     extract Xca planes (x,y,z) to compact fp32 buffer.
// ---------------------------------------------------------------------------
__global__ __launch_bounds__(256) void convert_kernel(
    const float* __restrict__ V, const float* __restrict__ W,
    const float* __restrict__ X,
    unsigned short* __restrict__ Vb, unsigned short* __restrict__ Wt,
    float* __restrict__ Xpl) {
    int bid = blockIdx.x;
    int t = threadIdx.x;
    if (bid < 1024) {
        // V: 1,048,576 floats, 4 per thread
        int g = bid * 256 + t;
        float4 v = ((const float4*)V)[g];
        ushort4 o;
        o.x = f2b(v.x); o.y = f2b(v.y); o.z = f2b(v.z); o.w = f2b(v.w);
        ((ushort4*)Vb)[g] = o;
    } else if (bid < 1424) {
        // Wt[n][c]: n<400 -> W[c,n]; n>=400 -> W[128+c, n-400]. 102,400 elems.
        int g = (bid - 1024) * 256 + t;
        int n = g >> 7, c = g & 127;
        float f = (n < OUTD) ? W[c * OUTD + n] : W[(IND + c) * OUTD + (n - OUTD)];
        Wt[g] = f2b(f);
    } else {
        // Xca planes: 3 * 8192 elems.  X[(m)*12 + 3 + c]
        int g = (bid - 1424) * 256 + t;   // [0, 24576)
        int c = g >> 13, m = g & 8191;
        Xpl[c * NQ + m] = X[(size_t)m * 12 + 3 + c];
    }
}

// ---------------------------------------------------------------------------
// K2: KNN.  One block (256 thr) per query.  Exact reference arithmetic
// (round-to-nearest mul/add/sqrt, no contraction), stable tie-break by index
// via u64 key = (f32bits(D_adjust) << 32) | j.
// ---------------------------------------------------------------------------
__global__ __launch_bounds__(256) void knn_kernel(
    const float* __restrict__ Xpl, const float* __restrict__ mask,
    int* __restrict__ idx_out, float* __restrict__ eidx_out) {
    __shared__ float sxx[LL], sxy[LL], sxz[LL], sm[LL];
    __shared__ unsigned long long wred[4];
    __shared__ unsigned long long bwin;
    __shared__ float smax[4];
    __shared__ float sDmax;

    int t = threadIdx.x;
    int wid = t >> 6, lane = t & 63;
    int q = blockIdx.x;
    int b = q >> 11, l = q & 2047;
    int base = b * LL;

    for (int i = t; i < LL; i += 256) {
        sxx[i] = Xpl[base + i];
        sxy[i] = Xpl[NQ + base + i];
        sxz[i] = Xpl[2 * NQ + base + i];
        sm[i]  = mask[base + i];
    }
    __syncthreads();

    float qx = sxx[l], qy = sxy[l], qz = sxz[l], qm = sm[l];

    float D[8], M2[8];
    float lmax = -1.0f;
    #pragma unroll
    for (int s = 0; s < 8; s++) {
        int j = t + 256 * s;
        float dx = __fsub_rn(qx, sxx[j]);
        float dy = __fsub_rn(qy, sxy[j]);
        float dz = __fsub_rn(qz, sxz[j]);
        float d2 = __fadd_rn(__fadd_rn(__fadd_rn(__fmul_rn(dx, dx), __fmul_rn(dy, dy)),
                                       __fmul_rn(dz, dz)), 1e-6f);
        float m2 = __fmul_rn(qm, sm[j]);
        float d = __fmul_rn(m2, __fsqrt_rn(d2));
        D[s] = d; M2[s] = m2;
        lmax = fmaxf(lmax, d);
    }
    // block max (for the mask-adjust term; exact 0 contribution when mask==1)
    #pragma unroll
    for (int off = 1; off < 64; off <<= 1)
        lmax = fmaxf(lmax, __shfl_xor(lmax, off));
    if (lane == 0) smax[wid] = lmax;
    __syncthreads();
    if (t == 0) {
        float m = fmaxf(fmaxf(smax[0], smax[1]), fmaxf(smax[2], smax[3]));
        sDmax = m;
    }
    __syncthreads();
    float Dmax = sDmax;

    unsigned long long keys[8];
    #pragma unroll
    for (int s = 0; s < 8; s++) {
        int j = t + 256 * s;
        float dadj = __fadd_rn(D[s], __fmul_rn(__fsub_rn(1.0f, M2[s]), Dmax));
        keys[s] = (((unsigned long long)__float_as_uint(dadj)) << 32) | (unsigned int)j;
    }

    size_t qb = (size_t)q * KNB;
    for (int k = 0; k < KNB; k++) {
        unsigned long long lm = keys[0];
        #pragma unroll
        for (int s = 1; s < 8; s++) lm = (keys[s] < lm) ? keys[s] : lm;
        #pragma unroll
        for (int off = 1; off < 64; off <<= 1) {
            unsigned long long o = __shfl_xor(lm, off);
            lm = (o < lm) ? o : lm;
        }
        if (lane == 0) wred[wid] = lm;
        __syncthreads();
        if (t == 0) {
            unsigned long long m = wred[0];
            #pragma unroll
            for (int w = 1; w < 4; w++) m = (wred[w] < m) ? wred[w] : m;
            bwin = m;
            unsigned int j = (unsigned int)(m & 0xFFFFFFFFull);
            idx_out[qb + k] = (int)j;
            eidx_out[qb + k] = (float)j;
        }
        __syncthreads();
        unsigned int j = (unsigned int)(bwin & 0xFFFFFFFFull);
        if ((int)(j & 255u) == t) keys[j >> 8] = ~0ULL;
    }
}

// ---------------------------------------------------------------------------
// K3: TU = Vb(8192x128) @ Wt^T  -> bf16 TU (8192x800).  One wave per 16x16
// tile, K=128 via 4x mfma_f32_16x16x32_bf16.
// ---------------------------------------------------------------------------
__global__ __launch_bounds__(256) void gemm_kernel(
    const unsigned short* __restrict__ Vb, const unsigned short* __restrict__ Wt,
    unsigned short* __restrict__ TU) {
    int wid = threadIdx.x >> 6, lane = threadIdx.x & 63;
    int tile = blockIdx.x * 4 + wid;       // 25600 tiles
    int tm = tile / 50, tn = tile % 50;
    int r16 = lane & 15, quad = lane >> 4;

    const unsigned short* Abase = Vb + (size_t)(tm * 16 + r16) * IND + quad * 8;
    const unsigned short* Bbase = Wt + (size_t)(tn * 16 + r16) * IND + quad * 8;

    f32x4 acc = {0.f, 0.f, 0.f, 0.f};
    #pragma unroll
    for (int kk = 0; kk < IND; kk += 32) {
        short8 a = *(const short8*)(Abase + kk);
        short8 b = *(const short8*)(Bbase + kk);
        acc = __builtin_amdgcn_mfma_f32_16x16x32_bf16(a, b, acc, 0, 0, 0);
    }
    int col = lane & 15;
    #pragma unroll
    for (int r = 0; r < 4; r++) {
        int m = tm * 16 + quad * 4 + r;
        TU[(size_t)m * NGEMM + tn * 16 + col] = f2b(acc[r]);
    }
}

// ---------------------------------------------------------------------------
// K4: epilogue.  One wave per (b,l): out[k,:] = T[i0,:] + U[j_k,:] + bias.
// ---------------------------------------------------------------------------
__global__ __launch_bounds__(256) void epi_kernel(
    const unsigned short* __restrict__ TU, const int* __restrict__ idx,
    const float* __restrict__ bias, float* __restrict__ out) {
    int wid = threadIdx.x >> 6, lane = threadIdx.x & 63;
    int q = blockIdx.x * 4 + wid;      // 8192
    int b = q >> 11;
    const int* mi = idx + (size_t)q * KNB;
    int i0 = mi[0];
    size_t rowT = ((size_t)(b * LL) + i0) * NGEMM;

    float t0[4], t1[4];
    {
        ushort4 u = *(const ushort4*)(TU + rowT + lane * 4);
        t0[0] = b2f(u.x) + bias[lane * 4 + 0];
        t0[1] = b2f(u.y) + bias[lane * 4 + 1];
        t0[2] = b2f(u.z) + bias[lane * 4 + 2];
        t0[3] = b2f(u.w) + bias[lane * 4 + 3];
    }
    bool has2 = lane < 36;
    if (has2) {
        int c = lane + 64;
        ushort4 u = *(const ushort4*)(TU + rowT + c * 4);
        t1[0] = b2f(u.x) + bias[c * 4 + 0];
        t1[1] = b2f(u.y) + bias[c * 4 + 1];
        t1[2] = b2f(u.z) + bias[c * 4 + 2];
        t1[3] = b2f(u.w) + bias[c * 4 + 3];
    }

    size_t outbase = (size_t)q * KNB * OUTD;
    for (int k = 0; k < KNB; k++) {
        int j = mi[k];
        size_t rowU = ((size_t)(b * LL) + j) * NGEMM + OUTD;
        float* orow = out + outbase + (size_t)k * OUTD;
        ushort4 u = *(const ushort4*)(TU + rowU + lane * 4);
        float4 o;
        o.x = t0[0] + b2f(u.x);
        o.y = t0[1] + b2f(u.y);
        o.z = t0[2] + b2f(u.z);
        o.w = t0[3] + b2f(u.w);
        *(float4*)(orow + lane * 4) = o;
        if (has2) {
            int c = lane + 64;
            ushort4 u2 = *(const ushort4*)(TU + rowU + c * 4);
            float4 o2;
            o2.x = t1[0] + b2f(u2.x);
            o2.y = t1[1] + b2f(u2.y);
            o2.z = t1[2] + b2f(u2.z);
            o2.w = t1[3] + b2f(u2.w);
            *(float4*)(orow + c * 4) = o2;
        }
    }
}

extern "C" void kernel_launch(void* const* d_in, const int* in_sizes, int n_in,
                              void* d_out, int out_size, void* d_ws, size_t ws_size,
                              hipStream_t stream) {
    const float* X    = (const float*)d_in[0];
    const float* mask = (const float*)d_in[1];
    const float* V    = (const float*)d_in[2];
    const float* W    = (const float*)d_in[3];
    const float* bias = (const float*)d_in[4];
    float* out = (float*)d_out;

    char* ws = (char*)d_ws;
    unsigned short* Vb  = (unsigned short*)(ws);                 // 2,097,152 B
    unsigned short* Wt  = (unsigned short*)(ws + 2097152);       //   204,800 B
    float*          Xpl = (float*)(ws + 2301952);                //    98,304 B
    int*            idx = (int*)(ws + 2400256);                  //   983,040 B
    unsigned short* TU  = (unsigned short*)(ws + 3383296);       // 13,107,200 B
    // total ws use: ~15.7 MB

    convert_kernel<<<1520, 256, 0, stream>>>(V, W, X, Vb, Wt, Xpl);
    knn_kernel<<<NQ, 256, 0, stream>>>(Xpl, mask, idx, out + OUT_EIDX_OFF);
    gemm_kernel<<<6400, 256, 0, stream>>>(Vb, Wt, TU);
    epi_kernel<<<NQ / 4, 256, 0, stream>>>(TU, idx, bias, out);
}

// Round 2
// 560.933 us; speedup vs baseline: 1.2084x; 1.2084x over previous
//
#include <hip/hip_runtime.h>
#include <hip/hip_bf16.h>
#include <stdint.h>
#include <stddef.h>

// Problem constants
#define BB 4
#define LL 2048
#define KNB 30
#define IND 128
#define OUTD 400
#define NGEMM 800           // 2*OUTD: [T | U] combined GEMM width
#define NQ (BB*LL)          // 8192 queries / rows
#define OUT_EIDX_OFF 98304000  // 4*2048*30*400

typedef short short8 __attribute__((ext_vector_type(8)));
typedef float f32x4 __attribute__((ext_vector_type(4)));

__device__ __forceinline__ unsigned short f2b(float f) {
    unsigned int u = __float_as_uint(f);
    unsigned int r = (u + 0x7FFFu + ((u >> 16) & 1u)) >> 16;  // RNE
    return (unsigned short)r;
}
__device__ __forceinline__ float b2f(unsigned short u) {
    return __uint_as_float(((unsigned int)u) << 16);
}

// ---------------------------------------------------------------------------
// K1: convert V -> bf16 (Vb), build transposed+concatenated W -> bf16 (Wt),
//     extract Xca planes (x,y,z) to compact fp32 buffer.
// ---------------------------------------------------------------------------
__global__ __launch_bounds__(256) void convert_kernel(
    const float* __restrict__ V, const float* __restrict__ W,
    const float* __restrict__ X,
    unsigned short* __restrict__ Vb, unsigned short* __restrict__ Wt,
    float* __restrict__ Xpl) {
    int bid = blockIdx.x;
    int t = threadIdx.x;
    if (bid < 1024) {
        // V: 1,048,576 floats, 4 per thread
        int g = bid * 256 + t;
        float4 v = ((const float4*)V)[g];
        ushort4 o;
        o.x = f2b(v.x); o.y = f2b(v.y); o.z = f2b(v.z); o.w = f2b(v.w);
        ((ushort4*)Vb)[g] = o;
    } else if (bid < 1424) {
        // Wt[n][c]: n<400 -> W[c,n]; n>=400 -> W[128+c, n-400]. 102,400 elems.
        int g = (bid - 1024) * 256 + t;
        int n = g >> 7, c = g & 127;
        float f = (n < OUTD) ? W[c * OUTD + n] : W[(IND + c) * OUTD + (n - OUTD)];
        Wt[g] = f2b(f);
    } else {
        // Xca planes: 3 * 8192 elems.  X[(m)*12 + 3 + c]
        int g = (bid - 1424) * 256 + t;   // [0, 24576)
        int c = g >> 13, m = g & 8191;
        Xpl[c * NQ + m] = X[(size_t)m * 12 + 3 + c];
    }
}

// ---------------------------------------------------------------------------
// K2: KNN.  One WAVE per query (4 waves/block share the coord tile).
// Exact reference arithmetic (round-to-nearest mul/add/sqrt, no contraction),
// stable tie-break by index via u64 key = (f32bits(D_adjust) << 32) | j.
// All per-lane arrays use compile-time indices only -> registers, no scratch.
// ---------------------------------------------------------------------------
__global__ __launch_bounds__(256) void knn_kernel(
    const float* __restrict__ Xpl, const float* __restrict__ mask,
    int* __restrict__ idx_out, float* __restrict__ eidx_out) {
    __shared__ float4 sc[LL];   // (x, y, z, mask) interleaved: one ds_read_b128/cand

    int t = threadIdx.x;
    int wid = t >> 6, lane = t & 63;
    int q = blockIdx.x * 4 + wid;        // 4 queries per block, same batch b
    int b = q >> 11, l = q & 2047;
    int base = b * LL;

    for (int i = t; i < LL; i += 256) {
        float4 c;
        c.x = Xpl[base + i];
        c.y = Xpl[NQ + base + i];
        c.z = Xpl[2 * NQ + base + i];
        c.w = mask[base + i];
        sc[i] = c;
    }
    __syncthreads();

    float4 qc = sc[l];
    float qx = qc.x, qy = qc.y, qz = qc.z, qm = qc.w;

    // Pass 1: distances + row max (for the mask-adjust term)
    float d[32], m2[32];
    float lmax = -1.0f;
    #pragma unroll
    for (int s = 0; s < 32; s++) {
        int j = lane + 64 * s;
        float4 c = sc[j];
        float dx = __fsub_rn(qx, c.x);
        float dy = __fsub_rn(qy, c.y);
        float dz = __fsub_rn(qz, c.z);
        float d2 = __fadd_rn(__fadd_rn(__fadd_rn(__fmul_rn(dx, dx), __fmul_rn(dy, dy)),
                                       __fmul_rn(dz, dz)), 1e-6f);
        float mm = __fmul_rn(qm, c.w);
        float dd = __fmul_rn(mm, __fsqrt_rn(d2));
        d[s] = dd; m2[s] = mm;
        lmax = fmaxf(lmax, dd);
    }
    #pragma unroll
    for (int off = 1; off < 64; off <<= 1)
        lmax = fmaxf(lmax, __shfl_xor(lmax, off));
    float Dmax = lmax;

    // Pass 2: u64 keys (value<<32 | index) -- ascending sort order == reference
    unsigned long long k64[32];
    #pragma unroll
    for (int s = 0; s < 32; s++) {
        float dadj = __fadd_rn(d[s], __fmul_rn(__fsub_rn(1.0f, m2[s]), Dmax));
        k64[s] = (((unsigned long long)__float_as_uint(dadj)) << 32)
               | (unsigned int)(lane + 64 * s);
    }

    // 30 extraction rounds: masked unrolled scan + wave butterfly min.
    unsigned int removed = 0u;
    unsigned int myj = 0u;
    for (int k = 0; k < KNB; k++) {
        unsigned long long lm = ~0ULL;
        #pragma unroll
        for (int s = 0; s < 32; s++) {
            unsigned long long key = ((removed >> s) & 1u) ? ~0ULL : k64[s];
            lm = (key < lm) ? key : lm;
        }
        #pragma unroll
        for (int off = 1; off < 64; off <<= 1) {
            unsigned long long o = __shfl_xor(lm, off);
            lm = (o < lm) ? o : lm;
        }
        unsigned int j = (unsigned int)lm;
        if ((int)(j & 63u) == lane) removed |= (1u << (j >> 6));
        if (lane == k) myj = j;
    }
    size_t qb = (size_t)q * KNB;
    if (lane < KNB) {
        idx_out[qb + lane] = (int)myj;
        eidx_out[qb + lane] = (float)myj;
    }
}

// ---------------------------------------------------------------------------
// K3: TU = Vb(8192x128) @ Wt^T  -> bf16 TU (8192x800).  One wave per 16x16
// tile, K=128 via 4x mfma_f32_16x16x32_bf16.
// ---------------------------------------------------------------------------
__global__ __launch_bounds__(256) void gemm_kernel(
    const unsigned short* __restrict__ Vb, const unsigned short* __restrict__ Wt,
    unsigned short* __restrict__ TU) {
    int wid = threadIdx.x >> 6, lane = threadIdx.x & 63;
    int tile = blockIdx.x * 4 + wid;       // 25600 tiles
    int tm = tile / 50, tn = tile % 50;
    int r16 = lane & 15, quad = lane >> 4;

    const unsigned short* Abase = Vb + (size_t)(tm * 16 + r16) * IND + quad * 8;
    const unsigned short* Bbase = Wt + (size_t)(tn * 16 + r16) * IND + quad * 8;

    f32x4 acc = {0.f, 0.f, 0.f, 0.f};
    #pragma unroll
    for (int kk = 0; kk < IND; kk += 32) {
        short8 a = *(const short8*)(Abase + kk);
        short8 b = *(const short8*)(Bbase + kk);
        acc = __builtin_amdgcn_mfma_f32_16x16x32_bf16(a, b, acc, 0, 0, 0);
    }
    int col = lane & 15;
    #pragma unroll
    for (int r = 0; r < 4; r++) {
        int m = tm * 16 + quad * 4 + r;
        TU[(size_t)m * NGEMM + tn * 16 + col] = f2b(acc[r]);
    }
}

// ---------------------------------------------------------------------------
// K4: epilogue.  One wave per (b,l): out[k,:] = T[i0,:] + U[j_k,:] + bias.
// ---------------------------------------------------------------------------
__global__ __launch_bounds__(256) void epi_kernel(
    const unsigned short* __restrict__ TU, const int* __restrict__ idx,
    const float* __restrict__ bias, float* __restrict__ out) {
    int wid = threadIdx.x >> 6, lane = threadIdx.x & 63;
    int q = blockIdx.x * 4 + wid;      // 8192
    int b = q >> 11;
    const int* mi = idx + (size_t)q * KNB;
    int i0 = mi[0];
    size_t rowT = ((size_t)(b * LL) + i0) * NGEMM;

    float t0[4], t1[4];
    {
        ushort4 u = *(const ushort4*)(TU + rowT + lane * 4);
        t0[0] = b2f(u.x) + bias[lane * 4 + 0];
        t0[1] = b2f(u.y) + bias[lane * 4 + 1];
        t0[2] = b2f(u.z) + bias[lane * 4 + 2];
        t0[3] = b2f(u.w) + bias[lane * 4 + 3];
    }
    bool has2 = lane < 36;
    if (has2) {
        int c = lane + 64;
        ushort4 u = *(const ushort4*)(TU + rowT + c * 4);
        t1[0] = b2f(u.x) + bias[c * 4 + 0];
        t1[1] = b2f(u.y) + bias[c * 4 + 1];
        t1[2] = b2f(u.z) + bias[c * 4 + 2];
        t1[3] = b2f(u.w) + bias[c * 4 + 3];
    }

    size_t outbase = (size_t)q * KNB * OUTD;
    for (int k = 0; k < KNB; k++) {
        int j = mi[k];
        size_t rowU = ((size_t)(b * LL) + j) * NGEMM + OUTD;
        float* orow = out + outbase + (size_t)k * OUTD;
        ushort4 u = *(const ushort4*)(TU + rowU + lane * 4);
        float4 o;
        o.x = t0[0] + b2f(u.x);
        o.y = t0[1] + b2f(u.y);
        o.z = t0[2] + b2f(u.z);
        o.w = t0[3] + b2f(u.w);
        *(float4*)(orow + lane * 4) = o;
        if (has2) {
            int c = lane + 64;
            ushort4 u2 = *(const ushort4*)(TU + rowU + c * 4);
            float4 o2;
            o2.x = t1[0] + b2f(u2.x);
            o2.y = t1[1] + b2f(u2.y);
            o2.z = t1[2] + b2f(u2.z);
            o2.w = t1[3] + b2f(u2.w);
            *(float4*)(orow + c * 4) = o2;
        }
    }
}

extern "C" void kernel_launch(void* const* d_in, const int* in_sizes, int n_in,
                              void* d_out, int out_size, void* d_ws, size_t ws_size,
                              hipStream_t stream) {
    const float* X    = (const float*)d_in[0];
    const float* mask = (const float*)d_in[1];
    const float* V    = (const float*)d_in[2];
    const float* W    = (const float*)d_in[3];
    const float* bias = (const float*)d_in[4];
    float* out = (float*)d_out;

    char* ws = (char*)d_ws;
    unsigned short* Vb  = (unsigned short*)(ws);                 // 2,097,152 B
    unsigned short* Wt  = (unsigned short*)(ws + 2097152);       //   204,800 B
    float*          Xpl = (float*)(ws + 2301952);                //    98,304 B
    int*            idx = (int*)(ws + 2400256);                  //   983,040 B
    unsigned short* TU  = (unsigned short*)(ws + 3383296);       // 13,107,200 B
    // total ws use: ~15.7 MB

    convert_kernel<<<1520, 256, 0, stream>>>(V, W, X, Vb, Wt, Xpl);
    knn_kernel<<<NQ / 4, 256, 0, stream>>>(Xpl, mask, idx, out + OUT_EIDX_OFF);
    gemm_kernel<<<6400, 256, 0, stream>>>(Vb, Wt, TU);
    epi_kernel<<<NQ / 4, 256, 0, stream>>>(TU, idx, bias, out);
}